// Round 12
// baseline (382.994 us; speedup 1.0000x reference)
//
#include <hip/hip_runtime.h>
#include <hip/hip_bf16.h>

typedef __attribute__((ext_vector_type(8))) short short8;
typedef __attribute__((ext_vector_type(4))) float f32x4;

__device__ __forceinline__ unsigned short f2bf(float v) {
    __hip_bfloat16 h = __float2bfloat16(v);   // RNE
    return *reinterpret_cast<unsigned short*>(&h);
}
__device__ __forceinline__ float bf2f(unsigned short u) {
    union { unsigned int i; float f; } x;
    x.i = (unsigned int)u << 16;
    return x.f;
}
__device__ __forceinline__ void acc8(float* s, uint4 v) {
    s[0] += bf2f((unsigned short)(v.x & 0xffff));
    s[1] += bf2f((unsigned short)(v.x >> 16));
    s[2] += bf2f((unsigned short)(v.y & 0xffff));
    s[3] += bf2f((unsigned short)(v.y >> 16));
    s[4] += bf2f((unsigned short)(v.z & 0xffff));
    s[5] += bf2f((unsigned short)(v.z >> 16));
    s[6] += bf2f((unsigned short)(v.w & 0xffff));
    s[7] += bf2f((unsigned short)(v.w >> 16));
}
__device__ __forceinline__ uint4 pack8(const float* s) {
    uint4 u;
    u.x = (unsigned int)f2bf(s[0]) | ((unsigned int)f2bf(s[1]) << 16);
    u.y = (unsigned int)f2bf(s[2]) | ((unsigned int)f2bf(s[3]) << 16);
    u.z = (unsigned int)f2bf(s[4]) | ((unsigned int)f2bf(s[5]) << 16);
    u.w = (unsigned int)f2bf(s[6]) | ((unsigned int)f2bf(s[7]) << 16);
    return u;
}

constexpr int MAXB = 2048;   // max fine buckets (N/64 = 1563 here)

// ---------------------------------------------------------------------------
// Weight pre-transpose: Wt[(r*H + h)*64 + d] = bf16( r<R ? W[r][d][h]
//                                                        : Wself[d][h] ).
// ---------------------------------------------------------------------------
template<int H>
__global__ __launch_bounds__(256) void transpose_w(
    const float* __restrict__ W, const float* __restrict__ Wself,
    unsigned short* __restrict__ Wt, int R)
{
    int i = blockIdx.x * 256 + threadIdx.x;
    int total = (R + 1) * H * 64;
    if (i >= total) return;
    int d = i & 63;
    int hh = i >> 6;               // r*H + h
    int r = hh / H, h = hh % H;    // H compile-time -> shifts
    float v = (r < R) ? W[((size_t)r * 64 + d) * H + h]
                      : Wself[(size_t)d * H + h];
    Wt[i] = f2bf(v);
}

// ---------------------------------------------------------------------------
// MFMA relation GEMM (operand-swapped, depth-2 W prefetch). ABF: bf16 A input
// (layer2/h1). SBF: bf16 self-loop output (layer1 -> h1).
// ---------------------------------------------------------------------------
template<int H, int RT, bool ABF, bool SBF>
__global__ __launch_bounds__(512) void gemm_rel_mfma(
    const void* __restrict__ Av, const unsigned short* __restrict__ Wt,
    const float* __restrict__ bias,
    unsigned short* __restrict__ C, void* __restrict__ Cselfv,
    int N, int Rrt, int relu)
{
    constexpr int AS = 72;   // 144 B/row = 36 words = 4 mod 32 -> 2-way (free)
    __shared__ unsigned short As[64 * AS];
    const int R = RT ? RT : Rrt;
    const int tid = threadIdx.x;
    const int n0 = blockIdx.x * 64;

    if constexpr (ABF) {
        const unsigned short* A = (const unsigned short*)Av;
        int n = tid >> 3, d8 = (tid & 7) * 8;
        int gn = n0 + n;
        short8 u = {};
        if (gn < N) u = *(const short8*)&A[(size_t)gn * 64 + d8];
        if (relu) {
            #pragma unroll
            for (int j = 0; j < 8; ++j) {
                unsigned short x = (unsigned short)u[j];
                u[j] = (short)((x & 0x8000) ? 0 : x);   // bf16 relu = sign test
            }
        }
        *(short8*)&As[n * AS + d8] = u;
    } else {
        const float* A = (const float*)Av;
        #pragma unroll
        for (int i = 0; i < 2; ++i) {
            int lin = tid + i * 512;
            int n = lin >> 4;
            int d4 = (lin & 15) * 4;
            int gn = n0 + n;
            float4 v = make_float4(0.f, 0.f, 0.f, 0.f);
            if (gn < N) v = *(const float4*)&A[(size_t)gn * 64 + d4];
            if (relu) {
                v.x = fmaxf(v.x, 0.f); v.y = fmaxf(v.y, 0.f);
                v.z = fmaxf(v.z, 0.f); v.w = fmaxf(v.w, 0.f);
            }
            ushort4 u;
            u.x = f2bf(v.x); u.y = f2bf(v.y); u.z = f2bf(v.z); u.w = f2bf(v.w);
            *(ushort4*)&As[n * AS + d4] = u;
        }
    }

    const int w = tid >> 6, lane = tid & 63;
    const int m = lane & 15, quad = lane >> 4;
    const int wt = w & 3;        // node sub-tile (16 nodes)
    const int half = w >> 2;     // column half (H/2 cols)
    const int node = n0 + wt * 16 + m;

    __syncthreads();   // the only barrier

    short8 afrag[2];
    afrag[0] = *(const short8*)&As[(wt * 16 + m) * AS + 0 * 32 + quad * 8];
    afrag[1] = *(const short8*)&As[(wt * 16 + m) * AS + 1 * 32 + quad * 8];

    constexpr int NT = H / 32;   // col-tiles per wave (64->2, 32->1)

    auto wptr = [&](int r, int nt, int kc) {
        int colbase = half * (H / 2) + nt * 16;
        return (const short8*)&Wt[((size_t)(r * H + colbase + m)) * 64 + kc * 32 + quad * 8];
    };

    short8 wf0[NT][2], wf1[NT][2];
    #pragma unroll
    for (int nt = 0; nt < NT; ++nt) { wf0[nt][0] = *wptr(0, nt, 0); wf0[nt][1] = *wptr(0, nt, 1); }
    #pragma unroll
    for (int nt = 0; nt < NT; ++nt) { wf1[nt][0] = *wptr(1, nt, 0); wf1[nt][1] = *wptr(1, nt, 1); }

    #pragma unroll
    for (int r = 0; r <= R; ++r) {
        short8 wn[NT][2];
        if (r + 2 <= R) {
            #pragma unroll
            for (int nt = 0; nt < NT; ++nt) {
                wn[nt][0] = *wptr(r + 2, nt, 0);
                wn[nt][1] = *wptr(r + 2, nt, 1);
            }
        }

        f32x4 acc[NT];
        #pragma unroll
        for (int nt = 0; nt < NT; ++nt) {
            acc[nt] = (f32x4){0.f, 0.f, 0.f, 0.f};
            acc[nt] = __builtin_amdgcn_mfma_f32_16x16x32_bf16(wf0[nt][0], afrag[0], acc[nt], 0, 0, 0);
            acc[nt] = __builtin_amdgcn_mfma_f32_16x16x32_bf16(wf0[nt][1], afrag[1], acc[nt], 0, 0, 0);
        }

        if (r < R) {
            #pragma unroll
            for (int nt = 0; nt < NT; ++nt) {
                int colbase = half * (H / 2) + nt * 16;
                if (node < N) {
                    ushort4 u;
                    u.x = f2bf(acc[nt][0]); u.y = f2bf(acc[nt][1]);
                    u.z = f2bf(acc[nt][2]); u.w = f2bf(acc[nt][3]);
                    *(ushort4*)&C[((size_t)r * N + node) * H + colbase + quad * 4] = u;
                }
            }
        } else {
            #pragma unroll
            for (int nt = 0; nt < NT; ++nt) {
                int colbase = half * (H / 2) + nt * 16;
                if (node < N) {
                    float4 bv = *(const float4*)&bias[colbase + quad * 4];
                    if constexpr (SBF) {
                        unsigned short* Cs = (unsigned short*)Cselfv;
                        ushort4 u;
                        u.x = f2bf(acc[nt][0] + bv.x); u.y = f2bf(acc[nt][1] + bv.y);
                        u.z = f2bf(acc[nt][2] + bv.z); u.w = f2bf(acc[nt][3] + bv.w);
                        *(ushort4*)&Cs[(size_t)node * H + colbase + quad * 4] = u;
                    } else {
                        float* Cs = (float*)Cselfv;
                        float4 o = make_float4(acc[nt][0] + bv.x, acc[nt][1] + bv.y,
                                               acc[nt][2] + bv.z, acc[nt][3] + bv.w);
                        *(float4*)&Cs[(size_t)node * H + colbase + quad * 4] = o;
                    }
                }
            }
        }

        #pragma unroll
        for (int nt = 0; nt < NT; ++nt) {
            wf0[nt][0] = wf1[nt][0]; wf0[nt][1] = wf1[nt][1];
            wf1[nt][0] = wn[nt][0];  wf1[nt][1] = wn[nt][1];
        }
    }
}

// ---------------------------------------------------------------------------
// Bucket partition. Bucket = 64 consecutive dst nodes.
// Record: (et*N + src) << 6 | (dst & 63).
// ---------------------------------------------------------------------------
__global__ __launch_bounds__(256) void zero_int(int* __restrict__ p, int n) {
    int i = blockIdx.x * 256 + threadIdx.x;
    if (i < n) p[i] = 0;
}

__global__ __launch_bounds__(256) void fine_hist(
    const int* __restrict__ dst, int* __restrict__ ghist, int E, int B, int CH)
{
    __shared__ int hist[MAXB];
    const int t = threadIdx.x;
    const int e0 = blockIdx.x * CH, e1 = min(E, e0 + CH);
    for (int i = t; i < B; i += 256) hist[i] = 0;
    __syncthreads();
    for (int e = e0 + t; e < e1; e += 256) atomicAdd(&hist[dst[e] >> 6], 1);
    __syncthreads();
    for (int i = t; i < B; i += 256) {
        int h = hist[i];
        if (h) atomicAdd(&ghist[i], h);
    }
}

__global__ __launch_bounds__(256) void fine_scan(
    const int* __restrict__ ghist, int* __restrict__ bstart,
    int* __restrict__ cursor, int B, int E)
{
    __shared__ int ts[256];
    const int t = threadIdx.x;
    const int PER = (B + 255) / 256;   // <= 8
    int loc[8];
    int s = 0;
    for (int j = 0; j < PER; ++j) {
        int i = t * PER + j;
        loc[j] = (i < B) ? ghist[i] : 0;
        s += loc[j];
    }
    ts[t] = s;
    __syncthreads();
    for (int off = 1; off < 256; off <<= 1) {
        int x = (t >= off) ? ts[t - off] : 0;
        __syncthreads();
        ts[t] += x;
        __syncthreads();
    }
    int run = ts[t] - s;
    for (int j = 0; j < PER; ++j) {
        int i = t * PER + j;
        if (i < B) { bstart[i] = run; cursor[i] = run; }
        run += loc[j];
    }
    if (t == 255) bstart[B] = E;
}

__global__ __launch_bounds__(256) void partition_fine(
    const int* __restrict__ src, const int* __restrict__ dst,
    const int* __restrict__ et, int* __restrict__ cursor,
    int* __restrict__ rec, int E, int N, int B, int CH)
{
    __shared__ int hist[MAXB];
    __shared__ int base[MAXB];
    __shared__ int cnt[MAXB];
    const int t = threadIdx.x;
    const int e0 = blockIdx.x * CH, e1 = min(E, e0 + CH);

    for (int i = t; i < B; i += 256) hist[i] = 0;
    __syncthreads();
    for (int e = e0 + t; e < e1; e += 256) atomicAdd(&hist[dst[e] >> 6], 1);
    __syncthreads();
    for (int i = t; i < B; i += 256) {
        int h = hist[i];
        base[i] = h ? atomicAdd(&cursor[i], h) : 0;
        cnt[i] = 0;
    }
    __syncthreads();
    for (int e = e0 + t; e < e1; e += 256) {
        int d = dst[e];
        int b = d >> 6;
        int pos = base[b] + atomicAdd(&cnt[b], 1);
        rec[pos] = ((et[e] * N + src[e]) << 6) | (d & 63);
    }
}

// ---------------------------------------------------------------------------
// Per-bucket counting sort -> per-node CSR (row_ptr + eidx).
// ---------------------------------------------------------------------------
__global__ __launch_bounds__(256) void bucket_sort(
    const int* __restrict__ bstart, const int* __restrict__ rec,
    int* __restrict__ eidx, int* __restrict__ row_ptr, int N, int E)
{
    __shared__ int hist[64];
    __shared__ int excl[64];
    __shared__ int cur[64];
    const int b = blockIdx.x;
    const int tid = threadIdx.x;
    const int p0 = bstart[b], p1 = bstart[b + 1];

    if (tid < 64) hist[tid] = 0;
    __syncthreads();
    for (int p = p0 + tid; p < p1; p += 256)
        atomicAdd(&hist[rec[p] & 63], 1);
    __syncthreads();
    if (tid == 0) {
        int run = 0;
        #pragma unroll
        for (int i = 0; i < 64; ++i) { excl[i] = run; run += hist[i]; }
    }
    __syncthreads();
    if (tid < 64) {
        cur[tid] = excl[tid];
        int n = b * 64 + tid;
        if (n < N) row_ptr[n] = p0 + excl[tid];
    }
    if (b == 0 && tid == 0) row_ptr[N] = E;
    __syncthreads();
    for (int p = p0 + tid; p < p1; p += 256) {
        int rv = rec[p];
        int pos = p0 + atomicAdd(&cur[rv & 63], 1);
        eidx[pos] = rv >> 6;   // et*N + src
    }
}

// ---------------------------------------------------------------------------
// agg64: one wave per dst node; lane = (edge-group g of 8, col-group j of 8).
// Lane gathers uint4 (16 B) -> one wave instr = 8 full edge-rows (1 KB).
// 2-deep unroll = 16 edges in flight. Butterfly shfl_xor over g; g==0 lanes
// do the packed-bf16 RMW of h1.
// ---------------------------------------------------------------------------
__global__ __launch_bounds__(256) void agg_csr64(
    const uint4* __restrict__ hw, const int* __restrict__ row_ptr,
    const int* __restrict__ eidx, uint4* __restrict__ out, int N)
{
    const int d = blockIdx.x * 4 + (threadIdx.x >> 6);
    if (d >= N) return;
    const int lane = threadIdx.x & 63;
    const int g = lane >> 3, j = lane & 7;
    const int p0 = row_ptr[d], p1 = row_ptr[d + 1];
    float s[8] = {}, t[8] = {};
    int p = p0 + g;
    for (; p + 8 < p1; p += 16) {
        uint4 v0 = hw[(size_t)eidx[p] * 8 + j];
        uint4 v1 = hw[(size_t)eidx[p + 8] * 8 + j];
        acc8(s, v0);
        acc8(t, v1);
    }
    if (p < p1) acc8(s, hw[(size_t)eidx[p] * 8 + j]);
    #pragma unroll
    for (int k = 0; k < 8; ++k) s[k] += t[k];
    #pragma unroll
    for (int mask = 8; mask <= 32; mask <<= 1)
        #pragma unroll
        for (int k = 0; k < 8; ++k) s[k] += __shfl_xor(s[k], mask);
    if (g == 0) {
        uint4 cur = out[(size_t)d * 8 + j];
        float c[8];
        c[0] = bf2f((unsigned short)(cur.x & 0xffff)); c[1] = bf2f((unsigned short)(cur.x >> 16));
        c[2] = bf2f((unsigned short)(cur.y & 0xffff)); c[3] = bf2f((unsigned short)(cur.y >> 16));
        c[4] = bf2f((unsigned short)(cur.z & 0xffff)); c[5] = bf2f((unsigned short)(cur.z >> 16));
        c[6] = bf2f((unsigned short)(cur.w & 0xffff)); c[7] = bf2f((unsigned short)(cur.w >> 16));
        #pragma unroll
        for (int k = 0; k < 8; ++k) s[k] += c[k];
        out[(size_t)d * 8 + j] = pack8(s);
    }
}

// ---------------------------------------------------------------------------
// agg32: one wave per dst node; lane = (edge-group g of 16, col-group j of 4).
// One wave instr gathers 16 full 64-B edge-rows. fp32 output (d_out).
// ---------------------------------------------------------------------------
__global__ __launch_bounds__(256) void agg_csr32(
    const uint4* __restrict__ hw, const int* __restrict__ row_ptr,
    const int* __restrict__ eidx, float* __restrict__ out, int N)
{
    const int d = blockIdx.x * 4 + (threadIdx.x >> 6);
    if (d >= N) return;
    const int lane = threadIdx.x & 63;
    const int g = lane >> 2, j = lane & 3;
    const int p0 = row_ptr[d], p1 = row_ptr[d + 1];
    float s[8] = {}, t[8] = {};
    int p = p0 + g;
    for (; p + 16 < p1; p += 32) {
        uint4 v0 = hw[(size_t)eidx[p] * 4 + j];
        uint4 v1 = hw[(size_t)eidx[p + 16] * 4 + j];
        acc8(s, v0);
        acc8(t, v1);
    }
    if (p < p1) acc8(s, hw[(size_t)eidx[p] * 4 + j]);
    #pragma unroll
    for (int k = 0; k < 8; ++k) s[k] += t[k];
    #pragma unroll
    for (int mask = 4; mask <= 32; mask <<= 1)
        #pragma unroll
        for (int k = 0; k < 8; ++k) s[k] += __shfl_xor(s[k], mask);
    if (g == 0) {
        float4 c0 = *(const float4*)&out[(size_t)d * 32 + j * 8];
        float4 c1 = *(const float4*)&out[(size_t)d * 32 + j * 8 + 4];
        float4 o0 = make_float4(c0.x + s[0], c0.y + s[1], c0.z + s[2], c0.w + s[3]);
        float4 o1 = make_float4(c1.x + s[4], c1.y + s[5], c1.z + s[6], c1.w + s[7]);
        *(float4*)&out[(size_t)d * 32 + j * 8] = o0;
        *(float4*)&out[(size_t)d * 32 + j * 8 + 4] = o1;
    }
}

extern "C" void kernel_launch(void* const* d_in, const int* in_sizes, int n_in,
                              void* d_out, int out_size, void* d_ws, size_t ws_size,
                              hipStream_t stream)
{
    const float* feat = (const float*)d_in[0];
    const int*   src  = (const int*)d_in[1];
    const int*   dst  = (const int*)d_in[2];
    const int*   et   = (const int*)d_in[3];
    const float* W1   = (const float*)d_in[4];
    const float* Ws1  = (const float*)d_in[5];
    const float* b1   = (const float*)d_in[6];
    const float* W2   = (const float*)d_in[7];
    const float* Ws2  = (const float*)d_in[8];
    const float* b2   = (const float*)d_in[9];
    float* out = (float*)d_out;

    const int N = in_sizes[0] / 64;           // 100000
    const int E = in_sizes[1];                // 1600000
    const int R = in_sizes[4] / (64 * 64);    // 8
    const int B = (N + 63) / 64;              // 1563 fine buckets

    // Workspace layout
    unsigned short* hW  = (unsigned short*)d_ws;           // [R][N][64] bf16 (reused [R][N][32])
    unsigned short* h1  = hW + (size_t)R * N * 64;         // [N][64] bf16
    unsigned short* Wt1 = h1 + (size_t)N * 64;             // [(R+1)*64*64]
    unsigned short* Wt2 = Wt1 + (size_t)(R + 1) * 64 * 64; // [(R+1)*32*64]
    int*   ghist   = (int*)(Wt2 + (size_t)(R + 1) * 32 * 64);  // [B]
    int*   bstart  = ghist + B;                            // [B+1]
    int*   cursor  = bstart + (B + 1);                     // [B]
    int*   row_ptr = cursor + B;                           // [N+1]
    int*   rec     = row_ptr + (N + 1);                    // [E]
    int*   eidx    = rec + E;                              // [E]

    const dim3 blk(256);
    const int nblk64 = (N + 63) / 64;
    const int P  = 128;                       // partition blocks
    const int CH = (E + P - 1) / P;           // 12500 edges per block

    // ---- Weight pre-transpose (bf16, [r][h][d]) ----
    transpose_w<64><<<((R + 1) * 64 * 64 + 255) / 256, blk, 0, stream>>>(W1, Ws1, Wt1, R);
    transpose_w<32><<<((R + 1) * 32 * 64 + 255) / 256, blk, 0, stream>>>(W2, Ws2, Wt2, R);

    // ---- Build per-node CSR via bucket partition + per-bucket sort ----
    zero_int<<<(B + 255) / 256, blk, 0, stream>>>(ghist, B);
    fine_hist<<<P, blk, 0, stream>>>(dst, ghist, E, B, CH);
    fine_scan<<<1, blk, 0, stream>>>(ghist, bstart, cursor, B, E);
    partition_fine<<<P, blk, 0, stream>>>(src, dst, et, cursor, rec, E, N, B, CH);
    bucket_sort<<<B, blk, 0, stream>>>(bstart, rec, eidx, row_ptr, N, E);

    // ---- Layer 1 ---- (hW1 bf16 + self-loop bf16 into h1, fused)
    if (R == 8)
        gemm_rel_mfma<64, 8, false, true><<<nblk64, 512, 0, stream>>>(feat, Wt1, b1, hW, h1, N, R, 0);
    else
        gemm_rel_mfma<64, 0, false, true><<<nblk64, 512, 0, stream>>>(feat, Wt1, b1, hW, h1, N, R, 0);
    agg_csr64<<<dim3((N + 3) / 4), blk, 0, stream>>>((const uint4*)hW, row_ptr, eidx,
                                                     (uint4*)h1, N);

    // ---- Layer 2 ---- (bf16 A staging with bit-mask ReLU; self fp32 -> out)
    if (R == 8)
        gemm_rel_mfma<32, 8, true, false><<<nblk64, 512, 0, stream>>>(h1, Wt2, b2, hW, out, N, R, 1);
    else
        gemm_rel_mfma<32, 0, true, false><<<nblk64, 512, 0, stream>>>(h1, Wt2, b2, hW, out, N, R, 1);
    agg_csr32<<<dim3((N + 3) / 4), blk, 0, stream>>>((const uint4*)hW, row_ptr, eidx, out, N);
}